// Round 1
// 110.032 us; speedup vs baseline: 1.6946x; 1.6946x over previous
//
#include <hip/hip_runtime.h>

typedef _Float16 half8  __attribute__((ext_vector_type(8)));
typedef float    floatx4 __attribute__((ext_vector_type(4)));

#define KNRM_VOCAB 100000

// ======================= fast path (fp16 normalized table in ws) ==========

// Convert emb (100000 x 128 fp32) -> unit-normalized fp16 rows.
// One 16-lane group per row; grid 6250 x 256 covers exactly 100000 rows.
__global__ __launch_bounds__(256) void knrm_convert(
    const float* __restrict__ emb, _Float16* __restrict__ tab)
{
    const int row = blockIdx.x * 16 + (threadIdx.x >> 4);
    const int sub = threadIdx.x & 15;
    const float4* src = (const float4*)(emb + (size_t)row * 128 + sub * 8);
    const float4 v0 = src[0], v1 = src[1];
    float ns = v0.x*v0.x + v0.y*v0.y + v0.z*v0.z + v0.w*v0.w
             + v1.x*v1.x + v1.y*v1.y + v1.z*v1.z + v1.w*v1.w;
    ns += __shfl_xor(ns, 1); ns += __shfl_xor(ns, 2);
    ns += __shfl_xor(ns, 4); ns += __shfl_xor(ns, 8);
    const float inv = ns > 0.0f ? 1.0f / sqrtf(ns) : 0.0f;   // row 0 (padding) -> zeros
    half8 h;
    h[0] = (_Float16)(v0.x*inv); h[1] = (_Float16)(v0.y*inv);
    h[2] = (_Float16)(v0.z*inv); h[3] = (_Float16)(v0.w*inv);
    h[4] = (_Float16)(v1.x*inv); h[5] = (_Float16)(v1.y*inv);
    h[6] = (_Float16)(v1.z*inv); h[7] = (_Float16)(v1.w*inv);
    *(half8*)(tab + (size_t)row * 128 + sub * 8) = h;
}

// grid 1024 = 128 batches x 8 chunks of 256 tokens. 4 waves/block, each wave
// owns 4 tiles of 16 tokens; ALL 16 fragment gathers issued upfront (deep
// prefetch). MFMA operands swapped (A=doc, B=query) so C row=token,
// col=query: each lane accumulates ONE query's 11 bins -> pr[11] only.
__global__ __launch_bounds__(256, 4) void knrm_main_h(
    const int*      __restrict__ queries,    // 128 x 16
    const int*      __restrict__ documents,  // 128 x 2048
    const _Float16* __restrict__ tab,        // 100000 x 128, unit rows
    float*          __restrict__ partials)   // 1024 x 176, disjoint writes
{
    const int tid  = threadIdx.x;
    const int b    = blockIdx.x >> 3;
    const int tok0 = (blockIdx.x & 7) * 256;
    const int lane = tid & 63;
    const int wave = tid >> 6;
    const int col  = lane & 15;   // A row m / B col n select
    const int quad = lane >> 4;   // k-octet select / C row group

    // query fragments (B operand): fp16 load IS the fragment, no repack
    const int qi = queries[b * 16 + col];
    const _Float16* qp = tab + (size_t)qi * 128 + quad * 8;
    half8 qf[4];
#pragma unroll
    for (int c = 0; c < 4; ++c) qf[c] = *(const half8*)(qp + c * 32);

    int idx[4];
#pragma unroll
    for (int t = 0; t < 4; ++t)
        idx[t] = documents[b * 2048 + tok0 + (t * 4 + wave) * 16 + col];

    // deep prefetch: 16 x 16B gathers in flight per lane
    half8 d[4][4];
#pragma unroll
    for (int t = 0; t < 4; ++t) {
        const _Float16* rp = tab + (size_t)idx[t] * 128 + quad * 8;
#pragma unroll
        for (int c = 0; c < 4; ++c) d[t][c] = *(const half8*)(rp + c * 32);
    }

    float pr[11];
#pragma unroll
    for (int k = 0; k < 11; ++k) pr[k] = 0.0f;

#pragma unroll
    for (int t = 0; t < 4; ++t) {
        floatx4 acc = {0.0f, 0.0f, 0.0f, 0.0f};
#pragma unroll
        for (int c = 0; c < 4; ++c)
            acc = __builtin_amdgcn_mfma_f32_16x16x32_f16(d[t][c], qf[c], acc, 0, 0, 0);

        // C layout: col(lane&15)=query, row(quad*4+r)=token. Rows are unit
        // vectors => sim = acc[r] directly (eps diff ~1e-10 rel, negligible).
#pragma unroll
        for (int r = 0; r < 4; ++r) {
            const float s = acc[r];
#pragma unroll
            for (int k = 0; k < 11; ++k) {
                const float tt = s - (-1.0f + 0.2f * (float)k);
                // exp(-t^2/(2*0.1^2)) = exp2(-50*log2(e) * t^2)
                pr[k] += __builtin_amdgcn_exp2f(tt * tt * -72.13475204444817f);
            }
        }
    }

    // sum the 4 quads holding the same query column
#pragma unroll
    for (int k = 0; k < 11; ++k) {
        pr[k] += __shfl_xor(pr[k], 16);
        pr[k] += __shfl_xor(pr[k], 32);
    }

    __shared__ float ps[4][176];
    if (lane < 16) {
#pragma unroll
        for (int k = 0; k < 11; ++k) ps[wave][col * 11 + k] = pr[k];
    }
    __syncthreads();
    if (tid < 176)
        partials[blockIdx.x * 176 + tid] =
            ps[0][tid] + ps[1][tid] + ps[2][tid] + ps[3][tid];
}

// one block per batch: sum 8 chunk-partials, log, weighted reduce, sigmoid
__global__ __launch_bounds__(192) void knrm_final_h(
    const float* __restrict__ partials,
    const float* __restrict__ W,
    const float* __restrict__ bias,
    float*       __restrict__ out)
{
    const int b = blockIdx.x, t = threadIdx.x;
    float v = 0.0f;
    if (t < 176) {
        float s = 0.0f;
#pragma unroll
        for (int c = 0; c < 8; ++c) s += partials[(b * 8 + c) * 176 + t];
        const int k = t - (t / 11) * 11;           // t = q*11 + k
        v = __builtin_amdgcn_logf(s) * 0.69314718055994531f * W[k];
    }
#pragma unroll
    for (int off = 1; off < 64; off <<= 1) v += __shfl_xor(v, off);
    __shared__ float red[3];
    if ((t & 63) == 0) red[t >> 6] = v;
    __syncthreads();
    if (t == 0) {
        const float a = red[0] + red[1] + red[2] + bias[0];
        out[b] = __builtin_amdgcn_rcpf(1.0f + __builtin_amdgcn_exp2f(a * -1.4426950408889634f));
    }
}

// ======================= fallback path (original, fp32 gathers) ===========

__global__ __launch_bounds__(256) void knrm_zero(float* __restrict__ p) {
    p[blockIdx.x * 256 + threadIdx.x] = 0.0f;
}

__global__ __launch_bounds__(256) void knrm_main(
    const int*   __restrict__ queries,
    const int*   __restrict__ documents,
    const float* __restrict__ emb,
    float*       __restrict__ pooled)
{
    __shared__ __align__(16) _Float16 Qs[16][136];
    __shared__ float qn_s[16];
    __shared__ float pooled_s[176];

    const int tid  = threadIdx.x;
    const int b    = blockIdx.x >> 3;
    const int tok0 = (blockIdx.x & 7) * 256;

    {
        const int row = tid >> 4, sub = tid & 15;
        const int qi = queries[b * 16 + row];
        const float4* src = (const float4*)(emb + (size_t)qi * 128 + sub * 8);
        float4 v0 = src[0], v1 = src[1];
        half8 h;
        h[0] = (_Float16)v0.x; h[1] = (_Float16)v0.y;
        h[2] = (_Float16)v0.z; h[3] = (_Float16)v0.w;
        h[4] = (_Float16)v1.x; h[5] = (_Float16)v1.y;
        h[6] = (_Float16)v1.z; h[7] = (_Float16)v1.w;
        *(half8*)&Qs[row][sub * 8] = h;
        float ns = v0.x*v0.x + v0.y*v0.y + v0.z*v0.z + v0.w*v0.w
                 + v1.x*v1.x + v1.y*v1.y + v1.z*v1.z + v1.w*v1.w;
        ns += __shfl_xor(ns, 1); ns += __shfl_xor(ns, 2);
        ns += __shfl_xor(ns, 4); ns += __shfl_xor(ns, 8);
        if (sub == 0) qn_s[row] = sqrtf(ns);
    }
    if (tid < 176) pooled_s[tid] = 0.0f;
    __syncthreads();

    const int lane = tid & 63;
    const int wave = tid >> 6;
    const int col  = lane & 15;
    const int quad = lane >> 4;

    half8 afrag[4];
#pragma unroll
    for (int c = 0; c < 4; ++c)
        afrag[c] = *(const half8*)&Qs[col][c * 32 + quad * 8];

    float pr[4][11];
#pragma unroll
    for (int r = 0; r < 4; ++r)
#pragma unroll
        for (int k = 0; k < 11; ++k) pr[r][k] = 0.0f;

    int idx[4];
#pragma unroll
    for (int j = 0; j < 4; ++j)
        idx[j] = documents[b * 2048 + tok0 + (j * 4 + wave) * 16 + col];

    float4 cur[8];
    {
        const float* rp = emb + (size_t)idx[0] * 128 + quad * 8;
#pragma unroll
        for (int c = 0; c < 4; ++c) {
            cur[2*c]   = *(const float4*)(rp + c * 32);
            cur[2*c+1] = *(const float4*)(rp + c * 32 + 4);
        }
    }

    for (int j = 0; j < 4; ++j) {
        float4 nxt[8];
        if (j < 3) {
            const float* rp = emb + (size_t)idx[j + 1] * 128 + quad * 8;
#pragma unroll
            for (int c = 0; c < 4; ++c) {
                nxt[2*c]   = *(const float4*)(rp + c * 32);
                nxt[2*c+1] = *(const float4*)(rp + c * 32 + 4);
            }
        }

        half8 bf[4];
        float ns = 0.0f;
#pragma unroll
        for (int c = 0; c < 4; ++c) {
            float4 a = cur[2*c], dd = cur[2*c+1];
            half8 h;
            h[0] = (_Float16)a.x; h[1] = (_Float16)a.y;
            h[2] = (_Float16)a.z; h[3] = (_Float16)a.w;
            h[4] = (_Float16)dd.x; h[5] = (_Float16)dd.y;
            h[6] = (_Float16)dd.z; h[7] = (_Float16)dd.w;
            bf[c] = h;
            ns += a.x*a.x + a.y*a.y + a.z*a.z + a.w*a.w
                + dd.x*dd.x + dd.y*dd.y + dd.z*dd.z + dd.w*dd.w;
        }
        ns += __shfl_xor(ns, 16);
        ns += __shfl_xor(ns, 32);
        const float dn = sqrtf(ns);

        floatx4 acc = {0.0f, 0.0f, 0.0f, 0.0f};
#pragma unroll
        for (int c = 0; c < 4; ++c)
            acc = __builtin_amdgcn_mfma_f32_16x16x32_f16(afrag[c], bf[c], acc, 0, 0, 0);

#pragma unroll
        for (int r = 0; r < 4; ++r) {
            const float denom = qn_s[quad * 4 + r] * dn + 1e-8f;
            const float sim = acc[r] * __builtin_amdgcn_rcpf(denom);
#pragma unroll
            for (int k = 0; k < 11; ++k) {
                const float tt = sim - (-1.0f + 0.2f * (float)k);
                pr[r][k] += __builtin_amdgcn_exp2f(tt * tt * -72.13475204444817f);
            }
        }

#pragma unroll
        for (int i = 0; i < 8; ++i) cur[i] = nxt[i];
    }

#pragma unroll
    for (int r = 0; r < 4; ++r)
#pragma unroll
        for (int k = 0; k < 11; ++k)
            atomicAdd(&pooled_s[(quad * 4 + r) * 11 + k], pr[r][k]);
    __syncthreads();
    if (tid < 176) atomicAdd(&pooled[b * 176 + tid], pooled_s[tid]);
}

__global__ __launch_bounds__(128) void knrm_final(
    const float* __restrict__ pooled,
    const float* __restrict__ W,
    const float* __restrict__ bias,
    float*       __restrict__ out)
{
    const int b = threadIdx.x;
    float acc = bias[0];
#pragma unroll
    for (int k = 0; k < 11; ++k) {
        float s = 0.0f;
#pragma unroll
        for (int q = 0; q < 16; ++q)
            s += __builtin_amdgcn_logf(pooled[b * 176 + q * 11 + k]);
        acc += s * 0.69314718055994531f * W[k];
    }
    out[b] = __builtin_amdgcn_rcpf(1.0f + __builtin_amdgcn_exp2f(acc * -1.4426950408889634f));
}

// ==========================================================================

extern "C" void kernel_launch(void* const* d_in, const int* in_sizes, int n_in,
                              void* d_out, int out_size, void* d_ws, size_t ws_size,
                              hipStream_t stream) {
    const int*   queries   = (const int*)d_in[0];
    const int*   documents = (const int*)d_in[1];
    const float* emb       = (const float*)d_in[2];
    const float* W         = (const float*)d_in[3];
    const float* bias      = (const float*)d_in[4];
    float* out = (float*)d_out;

    const size_t TABB = (size_t)KNRM_VOCAB * 128 * sizeof(_Float16);  // 25.6 MB
    const size_t NEED = TABB + (size_t)1024 * 176 * sizeof(float);    // +720 KB

    if (ws_size >= NEED) {
        _Float16* tab      = (_Float16*)d_ws;
        float*    partials = (float*)((char*)d_ws + TABB);
        knrm_convert<<<6250, 256, 0, stream>>>(emb, tab);
        knrm_main_h<<<1024, 256, 0, stream>>>(queries, documents, tab, partials);
        knrm_final_h<<<128, 192, 0, stream>>>(partials, W, bias, out);
    } else {
        float* pooled = (float*)d_ws;   // 22528 floats = 88 KiB
        knrm_zero<<<88, 256, 0, stream>>>(pooled);
        knrm_main<<<1024, 256, 0, stream>>>(queries, documents, emb, pooled);
        knrm_final<<<1, 128, 0, stream>>>(pooled, W, bias, out);
    }
}

// Round 2
// 106.444 us; speedup vs baseline: 1.7517x; 1.0337x over previous
//
#include <hip/hip_runtime.h>

typedef _Float16 half8  __attribute__((ext_vector_type(8)));
typedef float    floatx4 __attribute__((ext_vector_type(4)));
typedef int      intx4  __attribute__((ext_vector_type(4)));
typedef char     char8  __attribute__((ext_vector_type(8)));

#define KNRM_VOCAB 100000

// ======================= fast path (i8 quantized table in ws) =============

// emb (100000 x 128 fp32) -> per-row-scaled i8 rows + fp32 dequant scales.
// quantized q_i = round(x_i * 127 / max|x|);  scale s = max|x| / (127*||x||)
// so s * q_i == x_i / ||x||  (unit-normalized), to quantization error.
// One 16-lane group per row; grid 6250 x 256 covers exactly 100000 rows.
__global__ __launch_bounds__(256) void knrm_convert_i8(
    const float* __restrict__ emb, char* __restrict__ tab,
    float* __restrict__ scales)
{
    const int row = blockIdx.x * 16 + (threadIdx.x >> 4);
    const int sub = threadIdx.x & 15;
    const float4* src = (const float4*)(emb + (size_t)row * 128 + sub * 8);
    const float4 v0 = src[0], v1 = src[1];
    float ns = v0.x*v0.x + v0.y*v0.y + v0.z*v0.z + v0.w*v0.w
             + v1.x*v1.x + v1.y*v1.y + v1.z*v1.z + v1.w*v1.w;
    float mx = fmaxf(fmaxf(fmaxf(fabsf(v0.x), fabsf(v0.y)), fmaxf(fabsf(v0.z), fabsf(v0.w))),
                     fmaxf(fmaxf(fabsf(v1.x), fabsf(v1.y)), fmaxf(fabsf(v1.z), fabsf(v1.w))));
    ns += __shfl_xor(ns, 1); ns += __shfl_xor(ns, 2);
    ns += __shfl_xor(ns, 4); ns += __shfl_xor(ns, 8);
    mx = fmaxf(mx, __shfl_xor(mx, 1)); mx = fmaxf(mx, __shfl_xor(mx, 2));
    mx = fmaxf(mx, __shfl_xor(mx, 4)); mx = fmaxf(mx, __shfl_xor(mx, 8));
    const bool nz = (ns > 0.0f);
    const float qm = nz ? 127.0f / mx : 0.0f;               // x -> i8
    const float s  = nz ? mx / (127.0f * sqrtf(ns)) : 0.0f; // i8 -> x/||x||
    char8 q;
    q[0] = (char)(int)rintf(v0.x * qm); q[1] = (char)(int)rintf(v0.y * qm);
    q[2] = (char)(int)rintf(v0.z * qm); q[3] = (char)(int)rintf(v0.w * qm);
    q[4] = (char)(int)rintf(v1.x * qm); q[5] = (char)(int)rintf(v1.y * qm);
    q[6] = (char)(int)rintf(v1.z * qm); q[7] = (char)(int)rintf(v1.w * qm);
    *(char8*)(tab + (size_t)row * 128 + sub * 8) = q;
    if (sub == 0) scales[row] = s;
}

// grid 1024 = 128 batches x 8 chunks of 256 tokens. 4 waves/block, each wave
// owns 4 tiles of 16 tokens; all doc-row gathers issued upfront. i8 rows are
// 128B = 2 cachelines/token (halved vs fp16) -> halves the MSHR-limited
// gather time. A=doc, B=query (identical linear fragment layout on both
// operands => k-permutation cancels). C row=token, col=query.
__global__ __launch_bounds__(256, 4) void knrm_main_i8(
    const int*   __restrict__ queries,    // 128 x 16
    const int*   __restrict__ documents,  // 128 x 2048
    const char*  __restrict__ tab,        // 100000 x 128 i8
    const float* __restrict__ scales,     // 100000 dequant scales (L2-resident)
    float*       __restrict__ partials)   // 1024 x 176, disjoint writes
{
    const int tid  = threadIdx.x;
    const int b    = blockIdx.x >> 3;
    const int tok0 = (blockIdx.x & 7) * 256;
    const int lane = tid & 63;
    const int wave = tid >> 6;
    const int col  = lane & 15;   // B col n select / C col (query)
    const int quad = lane >> 4;   // k-group select / C row group

    // query fragments (B operand): lane reads bytes c*64 + quad*16 of its row
    const int qi = queries[b * 16 + col];
    const float sq = scales[qi];
    const intx4* qp = (const intx4*)(tab + (size_t)qi * 128);
    intx4 qf[2];
#pragma unroll
    for (int c = 0; c < 2; ++c) qf[c] = qp[c * 4 + quad];

    int idx[4];
#pragma unroll
    for (int t = 0; t < 4; ++t)
        idx[t] = documents[b * 2048 + tok0 + (t * 4 + wave) * 16 + col];

    // deep prefetch: 8 x 16B doc gathers + 4 scale gathers in flight per lane
    intx4 d[4][2];
    float sdl[4];
#pragma unroll
    for (int t = 0; t < 4; ++t) {
        const intx4* rp = (const intx4*)(tab + (size_t)idx[t] * 128);
#pragma unroll
        for (int c = 0; c < 2; ++c) d[t][c] = rp[c * 4 + quad];
        sdl[t] = scales[idx[t]];
    }

    float pr[11];
#pragma unroll
    for (int k = 0; k < 11; ++k) pr[k] = 0.0f;

#pragma unroll
    for (int t = 0; t < 4; ++t) {
        intx4 acc = {0, 0, 0, 0};
#pragma unroll
        for (int c = 0; c < 2; ++c)
            acc = __builtin_amdgcn_mfma_i32_16x16x64_i8(d[t][c], qf[c], acc, 0, 0, 0);

        // C layout: col(lane&15)=query, row(quad*4+r)=token.
        // sim = acc * s_doc * s_q  (rows unit-normalized via scales)
#pragma unroll
        for (int r = 0; r < 4; ++r) {
            const float sd = __shfl(sdl[t], quad * 4 + r);  // lane col==token holds it
            const float s = (float)acc[r] * sd * sq;
#pragma unroll
            for (int k = 0; k < 11; ++k) {
                const float tt = s - (-1.0f + 0.2f * (float)k);
                // exp(-t^2/(2*0.1^2)) = exp2(-50*log2(e) * t^2)
                pr[k] += __builtin_amdgcn_exp2f(tt * tt * -72.13475204444817f);
            }
        }
    }

    // sum the 4 quads holding the same query column
#pragma unroll
    for (int k = 0; k < 11; ++k) {
        pr[k] += __shfl_xor(pr[k], 16);
        pr[k] += __shfl_xor(pr[k], 32);
    }

    __shared__ float ps[4][176];
    if (lane < 16) {
#pragma unroll
        for (int k = 0; k < 11; ++k) ps[wave][col * 11 + k] = pr[k];
    }
    __syncthreads();
    if (tid < 176)
        partials[blockIdx.x * 176 + tid] =
            ps[0][tid] + ps[1][tid] + ps[2][tid] + ps[3][tid];
}

// one block per batch: sum 8 chunk-partials, log, weighted reduce, sigmoid
__global__ __launch_bounds__(192) void knrm_final_h(
    const float* __restrict__ partials,
    const float* __restrict__ W,
    const float* __restrict__ bias,
    float*       __restrict__ out)
{
    const int b = blockIdx.x, t = threadIdx.x;
    float v = 0.0f;
    if (t < 176) {
        float s = 0.0f;
#pragma unroll
        for (int c = 0; c < 8; ++c) s += partials[(b * 8 + c) * 176 + t];
        const int k = t - (t / 11) * 11;           // t = q*11 + k
        v = __builtin_amdgcn_logf(s) * 0.69314718055994531f * W[k];
    }
#pragma unroll
    for (int off = 1; off < 64; off <<= 1) v += __shfl_xor(v, off);
    __shared__ float red[3];
    if ((t & 63) == 0) red[t >> 6] = v;
    __syncthreads();
    if (t == 0) {
        const float a = red[0] + red[1] + red[2] + bias[0];
        out[b] = __builtin_amdgcn_rcpf(1.0f + __builtin_amdgcn_exp2f(a * -1.4426950408889634f));
    }
}

// ======================= fallback path (original, fp32 gathers) ===========

__global__ __launch_bounds__(256) void knrm_zero(float* __restrict__ p) {
    p[blockIdx.x * 256 + threadIdx.x] = 0.0f;
}

__global__ __launch_bounds__(256) void knrm_main(
    const int*   __restrict__ queries,
    const int*   __restrict__ documents,
    const float* __restrict__ emb,
    float*       __restrict__ pooled)
{
    __shared__ __align__(16) _Float16 Qs[16][136];
    __shared__ float qn_s[16];
    __shared__ float pooled_s[176];

    const int tid  = threadIdx.x;
    const int b    = blockIdx.x >> 3;
    const int tok0 = (blockIdx.x & 7) * 256;

    {
        const int row = tid >> 4, sub = tid & 15;
        const int qi = queries[b * 16 + row];
        const float4* src = (const float4*)(emb + (size_t)qi * 128 + sub * 8);
        float4 v0 = src[0], v1 = src[1];
        half8 h;
        h[0] = (_Float16)v0.x; h[1] = (_Float16)v0.y;
        h[2] = (_Float16)v0.z; h[3] = (_Float16)v0.w;
        h[4] = (_Float16)v1.x; h[5] = (_Float16)v1.y;
        h[6] = (_Float16)v1.z; h[7] = (_Float16)v1.w;
        *(half8*)&Qs[row][sub * 8] = h;
        float ns = v0.x*v0.x + v0.y*v0.y + v0.z*v0.z + v0.w*v0.w
                 + v1.x*v1.x + v1.y*v1.y + v1.z*v1.z + v1.w*v1.w;
        ns += __shfl_xor(ns, 1); ns += __shfl_xor(ns, 2);
        ns += __shfl_xor(ns, 4); ns += __shfl_xor(ns, 8);
        if (sub == 0) qn_s[row] = sqrtf(ns);
    }
    if (tid < 176) pooled_s[tid] = 0.0f;
    __syncthreads();

    const int lane = tid & 63;
    const int wave = tid >> 6;
    const int col  = lane & 15;
    const int quad = lane >> 4;

    half8 afrag[4];
#pragma unroll
    for (int c = 0; c < 4; ++c)
        afrag[c] = *(const half8*)&Qs[col][c * 32 + quad * 8];

    float pr[4][11];
#pragma unroll
    for (int r = 0; r < 4; ++r)
#pragma unroll
        for (int k = 0; k < 11; ++k) pr[r][k] = 0.0f;

    int idx[4];
#pragma unroll
    for (int j = 0; j < 4; ++j)
        idx[j] = documents[b * 2048 + tok0 + (j * 4 + wave) * 16 + col];

    float4 cur[8];
    {
        const float* rp = emb + (size_t)idx[0] * 128 + quad * 8;
#pragma unroll
        for (int c = 0; c < 4; ++c) {
            cur[2*c]   = *(const float4*)(rp + c * 32);
            cur[2*c+1] = *(const float4*)(rp + c * 32 + 4);
        }
    }

    for (int j = 0; j < 4; ++j) {
        float4 nxt[8];
        if (j < 3) {
            const float* rp = emb + (size_t)idx[j + 1] * 128 + quad * 8;
#pragma unroll
            for (int c = 0; c < 4; ++c) {
                nxt[2*c]   = *(const float4*)(rp + c * 32);
                nxt[2*c+1] = *(const float4*)(rp + c * 32 + 4);
            }
        }

        half8 bf[4];
        float ns = 0.0f;
#pragma unroll
        for (int c = 0; c < 4; ++c) {
            float4 a = cur[2*c], dd = cur[2*c+1];
            half8 h;
            h[0] = (_Float16)a.x; h[1] = (_Float16)a.y;
            h[2] = (_Float16)a.z; h[3] = (_Float16)a.w;
            h[4] = (_Float16)dd.x; h[5] = (_Float16)dd.y;
            h[6] = (_Float16)dd.z; h[7] = (_Float16)dd.w;
            bf[c] = h;
            ns += a.x*a.x + a.y*a.y + a.z*a.z + a.w*a.w
                + dd.x*dd.x + dd.y*dd.y + dd.z*dd.z + dd.w*dd.w;
        }
        ns += __shfl_xor(ns, 16);
        ns += __shfl_xor(ns, 32);
        const float dn = sqrtf(ns);

        floatx4 acc = {0.0f, 0.0f, 0.0f, 0.0f};
#pragma unroll
        for (int c = 0; c < 4; ++c)
            acc = __builtin_amdgcn_mfma_f32_16x16x32_f16(afrag[c], bf[c], acc, 0, 0, 0);

#pragma unroll
        for (int r = 0; r < 4; ++r) {
            const float denom = qn_s[quad * 4 + r] * dn + 1e-8f;
            const float sim = acc[r] * __builtin_amdgcn_rcpf(denom);
#pragma unroll
            for (int k = 0; k < 11; ++k) {
                const float tt = sim - (-1.0f + 0.2f * (float)k);
                pr[r][k] += __builtin_amdgcn_exp2f(tt * tt * -72.13475204444817f);
            }
        }

#pragma unroll
        for (int i = 0; i < 8; ++i) cur[i] = nxt[i];
    }

#pragma unroll
    for (int r = 0; r < 4; ++r)
#pragma unroll
        for (int k = 0; k < 11; ++k)
            atomicAdd(&pooled_s[(quad * 4 + r) * 11 + k], pr[r][k]);
    __syncthreads();
    if (tid < 176) atomicAdd(&pooled[b * 176 + tid], pooled_s[tid]);
}

__global__ __launch_bounds__(128) void knrm_final(
    const float* __restrict__ pooled,
    const float* __restrict__ W,
    const float* __restrict__ bias,
    float*       __restrict__ out)
{
    const int b = threadIdx.x;
    float acc = bias[0];
#pragma unroll
    for (int k = 0; k < 11; ++k) {
        float s = 0.0f;
#pragma unroll
        for (int q = 0; q < 16; ++q)
            s += __builtin_amdgcn_logf(pooled[b * 176 + q * 11 + k]);
        acc += s * 0.69314718055994531f * W[k];
    }
    out[b] = __builtin_amdgcn_rcpf(1.0f + __builtin_amdgcn_exp2f(acc * -1.4426950408889634f));
}

// ==========================================================================

extern "C" void kernel_launch(void* const* d_in, const int* in_sizes, int n_in,
                              void* d_out, int out_size, void* d_ws, size_t ws_size,
                              hipStream_t stream) {
    const int*   queries   = (const int*)d_in[0];
    const int*   documents = (const int*)d_in[1];
    const float* emb       = (const float*)d_in[2];
    const float* W         = (const float*)d_in[3];
    const float* bias      = (const float*)d_in[4];
    float* out = (float*)d_out;

    const size_t TABB = (size_t)KNRM_VOCAB * 128;                    // 12.8 MB i8
    const size_t SCLB = (size_t)KNRM_VOCAB * sizeof(float);          // 400 KB
    const size_t NEED = TABB + SCLB + (size_t)1024 * 176 * sizeof(float);

    if (ws_size >= NEED) {
        char*  tab      = (char*)d_ws;
        float* scales   = (float*)((char*)d_ws + TABB);
        float* partials = (float*)((char*)d_ws + TABB + SCLB);
        knrm_convert_i8<<<6250, 256, 0, stream>>>(emb, tab, scales);
        knrm_main_i8<<<1024, 256, 0, stream>>>(queries, documents, tab, scales, partials);
        knrm_final_h<<<128, 192, 0, stream>>>(partials, W, bias, out);
    } else {
        float* pooled = (float*)d_ws;   // 22528 floats = 88 KiB
        knrm_zero<<<88, 256, 0, stream>>>(pooled);
        knrm_main<<<1024, 256, 0, stream>>>(queries, documents, emb, pooled);
        knrm_final<<<1, 128, 0, stream>>>(pooled, W, bias, out);
    }
}